// Round 1
// baseline (846.425 us; speedup 1.0000x reference)
//
#include <hip/hip_runtime.h>
#include <math.h>

// EdgeConv, factorized:
//   A[i] = x[i] @ (W1_top - W1_bot) + b1        (64-dim, per node)
//   B[j] = x[j] @ W1_bot                        (64-dim, per node)
//   agg1[i] = sum_{e: dst=i} relu(A[i] + B[src_e])
//   out[i]  = tanh(agg1[i] @ W2 + deg_i * b2)
//
// Edge bucketing: slot[dst*64 + pos] = src via int atomicAdd on cnt[dst].
// Capacity 64 per node: E=1.2M over N=100k -> Poisson(12), P(deg>64)~1e-30.

#define FDIM 64

// ---------------------------------------------------------------------------
// Kernel 1: per-node A,B precompute.  32 nodes/block, 4x4 register micro-tile.
// ---------------------------------------------------------------------------
__global__ __launch_bounds__(256) void node_pre(
    const float* __restrict__ x, const float* __restrict__ W1,
    const float* __restrict__ b1, float* __restrict__ A,
    float* __restrict__ Bm, int N)
{
    // Wc[k][c]: c<64 -> W1[k][c]-W1[64+k][c] ; c>=64 -> W1[64+k][c-64]
    __shared__ __align__(16) float Wc[64][132];   // pad 128->132 (16B-aligned rows)
    __shared__ __align__(16) float xsT[64][36];   // x tile transposed [k][node]

    const int tid = threadIdx.x;
    const int node0 = blockIdx.x * 32;

    for (int i = tid; i < 64 * 128; i += 256) {
        int k = i >> 7, c = i & 127;
        int cc = c & 63;
        float wb = W1[(64 + k) * 64 + cc];
        Wc[k][c] = (c < 64) ? (W1[k * 64 + cc] - wb) : wb;
    }
    for (int i = tid; i < 32 * 64; i += 256) {
        int n = i >> 6, k = i & 63;
        int gn = node0 + n;
        xsT[k][n] = (gn < N) ? x[(size_t)gn * 64 + k] : 0.f;
    }
    __syncthreads();

    const int cg = tid & 31, ng = tid >> 5;   // 32 col-groups x 8 node-groups
    const int c0 = cg * 4, n0 = ng * 4;

    float acc[4][4];
    #pragma unroll
    for (int ci = 0; ci < 4; ++ci) {
        float init = (c0 + ci < 64) ? b1[c0 + ci] : 0.f;
        acc[0][ci] = init; acc[1][ci] = init; acc[2][ci] = init; acc[3][ci] = init;
    }

    #pragma unroll
    for (int k = 0; k < 64; ++k) {
        float4 xv = *(const float4*)&xsT[k][n0];
        float4 wv = *(const float4*)&Wc[k][c0];
        acc[0][0] += xv.x * wv.x; acc[0][1] += xv.x * wv.y; acc[0][2] += xv.x * wv.z; acc[0][3] += xv.x * wv.w;
        acc[1][0] += xv.y * wv.x; acc[1][1] += xv.y * wv.y; acc[1][2] += xv.y * wv.z; acc[1][3] += xv.y * wv.w;
        acc[2][0] += xv.z * wv.x; acc[2][1] += xv.z * wv.y; acc[2][2] += xv.z * wv.z; acc[2][3] += xv.z * wv.w;
        acc[3][0] += xv.w * wv.x; acc[3][1] += xv.w * wv.y; acc[3][2] += xv.w * wv.z; acc[3][3] += xv.w * wv.w;
    }

    #pragma unroll
    for (int ni = 0; ni < 4; ++ni) {
        int n = node0 + n0 + ni;
        if (n >= N) break;
        float4 v = make_float4(acc[ni][0], acc[ni][1], acc[ni][2], acc[ni][3]);
        if (c0 < 64) ((float4*)A)[(size_t)n * 16 + (c0 >> 2)] = v;
        else         ((float4*)Bm)[(size_t)n * 16 + ((c0 - 64) >> 2)] = v;
    }
}

// ---------------------------------------------------------------------------
// Kernel 2: bucket edges by dst (counting-sort with fixed capacity 64).
// ---------------------------------------------------------------------------
__global__ __launch_bounds__(256) void scatter_k(
    const int* __restrict__ ei, int* __restrict__ slot,
    int* __restrict__ cnt, int E)
{
    int e = blockIdx.x * 256 + threadIdx.x;
    if (e >= E) return;
    int src = ei[e];
    int dst = ei[E + e];
    int pos = atomicAdd(&cnt[dst], 1);
    if (pos < 64) slot[(size_t)dst * 64 + pos] = src;
}

// ---------------------------------------------------------------------------
// Kernel 3: fused aggregate + W2 GEMM + deg*b2 + tanh.  16 nodes/block.
// Phase 1: one wave per 4 nodes, lane = feature; relu-accumulate B gathers.
// Phase 2: [16x64] @ W2 from LDS, tanh, store.
// ---------------------------------------------------------------------------
__global__ __launch_bounds__(256) void fused_agg(
    const float* __restrict__ A, const float* __restrict__ Bm,
    const int* __restrict__ slot, const int* __restrict__ cnt,
    const float* __restrict__ W2, const float* __restrict__ b2,
    float* __restrict__ out, int N)
{
    __shared__ __align__(16) float W2s[64][68];
    __shared__ __align__(16) float aggT[16][68];

    const int tid = threadIdx.x;
    const int node0 = blockIdx.x * 16;

    for (int i = tid; i < 4096; i += 256) {
        int k = i >> 6, c = i & 63;
        W2s[k][c] = W2[i];
    }

    const int lane = tid & 63, wave = tid >> 6;
    #pragma unroll
    for (int ni = 0; ni < 4; ++ni) {
        int nl = wave * 4 + ni;
        int n = node0 + nl;
        if (n < N) {
            float a = A[(size_t)n * 64 + lane];
            int d = cnt[n];
            d = min(d, 64);
            const int* sl = slot + (size_t)n * 64;
            int sv = (lane < d) ? sl[lane] : 0;   // all edge srcs, one per lane
            float acc = 0.f;
            for (int j = 0; j < d; ++j) {
                int s = __shfl(sv, j);            // broadcast edge j's src
                float b = Bm[(size_t)s * 64 + lane];
                acc += fmaxf(a + b, 0.f);
            }
            aggT[nl][lane] = acc;
        }
    }
    __syncthreads();

    const int cg = tid & 15, ng = tid >> 4;       // 16 cols-groups x 16 nodes
    const int c0 = cg * 4;
    int n = node0 + ng;
    if (n >= N) return;
    float dg = (float)cnt[n];
    float o0 = dg * b2[c0 + 0];
    float o1 = dg * b2[c0 + 1];
    float o2 = dg * b2[c0 + 2];
    float o3 = dg * b2[c0 + 3];
    #pragma unroll
    for (int k = 0; k < 64; ++k) {
        float av = aggT[ng][k];
        float4 wv = *(const float4*)&W2s[k][c0];
        o0 += av * wv.x; o1 += av * wv.y; o2 += av * wv.z; o3 += av * wv.w;
    }
    float4 r = make_float4(tanhf(o0), tanhf(o1), tanhf(o2), tanhf(o3));
    ((float4*)out)[(size_t)n * 16 + cg] = r;
}

// ---------------------------------------------------------------------------
extern "C" void kernel_launch(void* const* d_in, const int* in_sizes, int n_in,
                              void* d_out, int out_size, void* d_ws, size_t ws_size,
                              hipStream_t stream)
{
    const float* x  = (const float*)d_in[0];
    const int*   ei = (const int*)d_in[1];     // [2,E]: row0=src, row1=dst
    const float* W1 = (const float*)d_in[2];   // [128,64]
    const float* b1 = (const float*)d_in[3];   // [64]
    const float* W2 = (const float*)d_in[4];   // [64,64]
    const float* b2 = (const float*)d_in[5];   // [64]
    float* out = (float*)d_out;

    const int N = in_sizes[0] / FDIM;          // 100000
    const int E = in_sizes[1] / 2;             // 1200000

    // Workspace layout (ws poisoned 0xAA every call -> zero cnt ourselves):
    float* A    = (float*)d_ws;                         // N*64 f32 = 25.6 MB
    float* Bm   = A + (size_t)N * FDIM;                 // N*64 f32 = 25.6 MB
    int*   slot = (int*)(Bm + (size_t)N * FDIM);        // N*64 i32 = 25.6 MB
    int*   cnt  = slot + (size_t)N * FDIM;              // N   i32 =  0.4 MB

    hipMemsetAsync(cnt, 0, (size_t)N * sizeof(int), stream);

    node_pre<<<(N + 31) / 32, 256, 0, stream>>>(x, W1, b1, A, Bm, N);
    scatter_k<<<(E + 255) / 256, 256, 0, stream>>>(ei, slot, cnt, E);
    fused_agg<<<(N + 15) / 16, 256, 0, stream>>>(A, Bm, slot, cnt, W2, b2, out, N);
}

// Round 2
// 297.365 us; speedup vs baseline: 2.8464x; 2.8464x over previous
//
#include <hip/hip_runtime.h>
#include <math.h>

// EdgeConv, factorized:
//   A[i] = x[i] @ (W1_top - W1_bot) + b1        (64-dim, per node)
//   B[j] = x[j] @ W1_bot                        (64-dim, per node)
//   agg1[i] = sum_{e: dst=i} relu(A[i] + B[src_e])
//   out[i]  = tanh(agg1[i] @ W2 + deg_i * b2)
//
// Edge bucketing: slot[dst*64 + pos] = src via int atomicAdd on cnt[dst].
// Capacity 64 per node: E=1.2M over N=100k -> Poisson(12), P(deg>64)~1e-30.

#define FDIM 64

// ---------------------------------------------------------------------------
// Kernel 1: per-node A,B precompute.  64 nodes/block, 256 threads.
// Thread (ng=tid&15, cg=tid>>4) computes nodes 4*ng..+3, cols 8*cg..+7.
// Lane mapping: 16 consecutive lanes share cg -> Wc reads broadcast; xsT
// float4 reads are 2-way (free).
// ---------------------------------------------------------------------------
__global__ __launch_bounds__(256) void node_pre(
    const float* __restrict__ x, const float* __restrict__ W1,
    const float* __restrict__ b1, float* __restrict__ A,
    float* __restrict__ Bm, int N)
{
    // Wc[k][c]: c<64 -> W1[k][c]-W1[64+k][c] ; c>=64 -> W1[64+k][c-64]
    __shared__ __align__(16) float Wc[64][132];
    __shared__ __align__(16) float xsT[64][72];   // [k][node], pad 64->72

    const int tid = threadIdx.x;
    const int node0 = blockIdx.x * 64;

    for (int i = tid; i < 64 * 128; i += 256) {
        int k = i >> 7, c = i & 127;
        int cc = c & 63;
        float wb = W1[(64 + k) * 64 + cc];
        Wc[k][c] = (c < 64) ? (W1[k * 64 + cc] - wb) : wb;
    }
    for (int i = tid; i < 64 * 64; i += 256) {
        int n = i >> 6, k = i & 63;
        int gn = node0 + n;
        xsT[k][n] = (gn < N) ? x[(size_t)gn * 64 + k] : 0.f;
    }
    __syncthreads();

    const int ng = tid & 15, cg = tid >> 4;   // 16 node-groups x 16 col-groups
    const int n0 = ng * 4, c0 = cg * 8;

    float acc[4][8];
    #pragma unroll
    for (int ci = 0; ci < 8; ++ci) {
        float init = (c0 + ci < 64) ? b1[c0 + ci] : 0.f;
        #pragma unroll
        for (int ni = 0; ni < 4; ++ni) acc[ni][ci] = init;
    }

    #pragma unroll 4
    for (int k = 0; k < 64; ++k) {
        float4 xv = *(const float4*)&xsT[k][n0];
        float4 wa = *(const float4*)&Wc[k][c0];
        float4 wb = *(const float4*)&Wc[k][c0 + 4];
        float xs[4] = {xv.x, xv.y, xv.z, xv.w};
        float ws[8] = {wa.x, wa.y, wa.z, wa.w, wb.x, wb.y, wb.z, wb.w};
        #pragma unroll
        for (int ni = 0; ni < 4; ++ni)
            #pragma unroll
            for (int ci = 0; ci < 8; ++ci)
                acc[ni][ci] += xs[ni] * ws[ci];
    }

    #pragma unroll
    for (int ni = 0; ni < 4; ++ni) {
        int n = node0 + n0 + ni;
        if (n >= N) break;
        float4 v0 = make_float4(acc[ni][0], acc[ni][1], acc[ni][2], acc[ni][3]);
        float4 v1 = make_float4(acc[ni][4], acc[ni][5], acc[ni][6], acc[ni][7]);
        if (c0 < 64) {
            ((float4*)A)[(size_t)n * 16 + (c0 >> 2)] = v0;
            ((float4*)A)[(size_t)n * 16 + (c0 >> 2) + 1] = v1;
        } else {
            ((float4*)Bm)[(size_t)n * 16 + ((c0 - 64) >> 2)] = v0;
            ((float4*)Bm)[(size_t)n * 16 + ((c0 - 64) >> 2) + 1] = v1;
        }
    }
}

// ---------------------------------------------------------------------------
// Kernel 2: bucket edges by dst (counting-sort with fixed capacity 64).
// ---------------------------------------------------------------------------
__global__ __launch_bounds__(256) void scatter_k(
    const int* __restrict__ ei, int* __restrict__ slot,
    int* __restrict__ cnt, int E)
{
    int e = blockIdx.x * 256 + threadIdx.x;
    if (e >= E) return;
    int src = ei[e];
    int dst = ei[E + e];
    int pos = atomicAdd(&cnt[dst], 1);
    if (pos < 64) slot[(size_t)dst * 64 + pos] = src;
}

// ---------------------------------------------------------------------------
// Kernel 3: fused aggregate + W2 GEMM + deg*b2 + tanh.  32 nodes/block.
// Phase 1: thread (n = tid>>4, q = tid&15) owns float4 feature-quad q of
// node n (+16): edge loop unrolled x4 -> 4 independent coalesced float4
// gathers in flight per thread (~256 lines/wave outstanding).
// Phase 2: [32x64] @ W2 from LDS, tanh, store.
// ---------------------------------------------------------------------------
__device__ __forceinline__ float4 relu4add(float4 acc, float4 a, float4 b) {
    acc.x += fmaxf(a.x + b.x, 0.f);
    acc.y += fmaxf(a.y + b.y, 0.f);
    acc.z += fmaxf(a.z + b.z, 0.f);
    acc.w += fmaxf(a.w + b.w, 0.f);
    return acc;
}
__device__ __forceinline__ float4 relu4add_m(float4 acc, float4 a, float4 b, bool m) {
    acc.x += m ? fmaxf(a.x + b.x, 0.f) : 0.f;
    acc.y += m ? fmaxf(a.y + b.y, 0.f) : 0.f;
    acc.z += m ? fmaxf(a.z + b.z, 0.f) : 0.f;
    acc.w += m ? fmaxf(a.w + b.w, 0.f) : 0.f;
    return acc;
}

__global__ __launch_bounds__(256) void fused_agg(
    const float* __restrict__ A, const float* __restrict__ Bm,
    const int* __restrict__ slot, const int* __restrict__ cnt,
    const float* __restrict__ W2, const float* __restrict__ b2,
    float* __restrict__ out, int N)
{
    __shared__ __align__(16) float W2s[64][68];
    __shared__ __align__(16) float aggT[32][68];
    __shared__ int sls[32][64];
    __shared__ int degs[32];

    const int tid = threadIdx.x;
    const int node0 = blockIdx.x * 32;
    const float4* __restrict__ B4 = (const float4*)Bm;

    for (int i = tid; i < 4096; i += 256) W2s[i >> 6][i & 63] = W2[i];
    for (int i = tid; i < 2048; i += 256) {
        int n = i >> 6, p = i & 63;
        int gn = node0 + n;
        int v = 0;
        if (gn < N) {
            int c = cnt[gn];
            if (p < c) v = slot[(size_t)gn * 64 + p];
        }
        sls[n][p] = v;
    }
    if (tid < 32) {
        int gn = node0 + tid;
        degs[tid] = (gn < N) ? min(cnt[gn], 64) : 0;
    }
    __syncthreads();

    const int q = tid & 15;          // feature quad (consecutive 16 tids span a row)
    const int nbase = tid >> 4;      // node 0..15; also handles +16
    #pragma unroll
    for (int h = 0; h < 2; ++h) {
        int nl = nbase + h * 16;
        int gn = node0 + nl;
        int d = degs[nl];
        float4 a = make_float4(0.f, 0.f, 0.f, 0.f);
        if (gn < N) a = ((const float4*)A)[(size_t)gn * 16 + q];
        float4 acc = make_float4(0.f, 0.f, 0.f, 0.f);

        const int dfull = d & ~3;
        int j = 0;
        for (; j < dfull; j += 4) {
            int s0 = sls[nl][j + 0];
            int s1 = sls[nl][j + 1];
            int s2 = sls[nl][j + 2];
            int s3 = sls[nl][j + 3];
            float4 b0 = B4[(size_t)s0 * 16 + q];
            float4 b1v = B4[(size_t)s1 * 16 + q];
            float4 b2v = B4[(size_t)s2 * 16 + q];
            float4 b3v = B4[(size_t)s3 * 16 + q];
            acc = relu4add(acc, a, b0);
            acc = relu4add(acc, a, b1v);
            acc = relu4add(acc, a, b2v);
            acc = relu4add(acc, a, b3v);
        }
        if (j < d) {                 // tail: 1..3 edges, clamped + predicated
            int s0 = sls[nl][j];
            int s1 = sls[nl][min(j + 1, d - 1)];
            int s2 = sls[nl][min(j + 2, d - 1)];
            float4 b0 = B4[(size_t)s0 * 16 + q];
            float4 b1v = B4[(size_t)s1 * 16 + q];
            float4 b2v = B4[(size_t)s2 * 16 + q];
            acc = relu4add(acc, a, b0);
            acc = relu4add_m(acc, a, b1v, j + 1 < d);
            acc = relu4add_m(acc, a, b2v, j + 2 < d);
        }
        *(float4*)&aggT[nl][q * 4] = acc;
    }
    __syncthreads();

    const int cg = tid & 15, ng = tid >> 4;   // 16 col-groups x 16 nodes (+16)
    const int c0 = cg * 4;
    #pragma unroll
    for (int h = 0; h < 2; ++h) {
        int nl = ng + h * 16;
        int n = node0 + nl;
        if (n >= N) continue;
        float dg = (float)degs[nl];
        float o0 = dg * b2[c0 + 0];
        float o1 = dg * b2[c0 + 1];
        float o2 = dg * b2[c0 + 2];
        float o3 = dg * b2[c0 + 3];
        #pragma unroll 8
        for (int k = 0; k < 64; ++k) {
            float av = aggT[nl][k];
            float4 wv = *(const float4*)&W2s[k][c0];
            o0 += av * wv.x; o1 += av * wv.y; o2 += av * wv.z; o3 += av * wv.w;
        }
        float4 r = make_float4(tanhf(o0), tanhf(o1), tanhf(o2), tanhf(o3));
        ((float4*)out)[(size_t)n * 16 + cg] = r;
    }
}

// ---------------------------------------------------------------------------
extern "C" void kernel_launch(void* const* d_in, const int* in_sizes, int n_in,
                              void* d_out, int out_size, void* d_ws, size_t ws_size,
                              hipStream_t stream)
{
    const float* x  = (const float*)d_in[0];
    const int*   ei = (const int*)d_in[1];     // [2,E]: row0=src, row1=dst
    const float* W1 = (const float*)d_in[2];   // [128,64]
    const float* b1 = (const float*)d_in[3];   // [64]
    const float* W2 = (const float*)d_in[4];   // [64,64]
    const float* b2 = (const float*)d_in[5];   // [64]
    float* out = (float*)d_out;

    const int N = in_sizes[0] / FDIM;          // 100000
    const int E = in_sizes[1] / 2;             // 1200000

    // Workspace layout (ws poisoned 0xAA every call -> zero cnt ourselves):
    float* A    = (float*)d_ws;                         // N*64 f32 = 25.6 MB
    float* Bm   = A + (size_t)N * FDIM;                 // N*64 f32 = 25.6 MB
    int*   slot = (int*)(Bm + (size_t)N * FDIM);        // N*64 i32 = 25.6 MB
    int*   cnt  = slot + (size_t)N * FDIM;              // N   i32 =  0.4 MB

    hipMemsetAsync(cnt, 0, (size_t)N * sizeof(int), stream);

    node_pre<<<(N + 63) / 64, 256, 0, stream>>>(x, W1, b1, A, Bm, N);
    scatter_k<<<(E + 255) / 256, 256, 0, stream>>>(ei, slot, cnt, E);
    fused_agg<<<(N + 31) / 32, 256, 0, stream>>>(A, Bm, slot, cnt, W2, b2, out, N);
}